// Round 6
// baseline (308.276 us; speedup 1.0000x reference)
//
#include <hip/hip_runtime.h>
#include <math.h>

#define NB 32768
#define NT 48
#define NH 32
#define NOH 16
#define NK 3
#define NS 6
#define NSUB 4

typedef float f2 __attribute__((ext_vector_type(2)));

// Force a value to stay live in VGPRs (compiler cannot rematerialize)
#define PIN_V(x) asm volatile("" : "+v"(x))
// Make a wave-uniform float SGPR-resident (legal VGPR->SGPR via readfirstlane)
__device__ __forceinline__ float uni(float x) {
    return __int_as_float(__builtin_amdgcn_readfirstlane(__float_as_int(x)));
}
// wave-uniform lane-gather (value was loaded per-lane; index is SGPR-uniform)
__device__ __forceinline__ float lanef(float v, int l) {
    return __int_as_float(__builtin_amdgcn_readlane(__float_as_int(v), l));
}

__device__ __forceinline__ f2 fma2(f2 a, f2 b, f2 c) {
    return __builtin_elementwise_fma(a, b, c);
}
__device__ __forceinline__ f2 bc2(float x) { f2 r; r.x = x; r.y = x; return r; }

// partner-lane value via DPP quad_perm [1,0,3,2] (xor lane^1) — VALU pipe
__device__ __forceinline__ float dpp_xor1(float v) {
    int x = __builtin_amdgcn_update_dpp(0, __float_as_int(v), 0xB1, 0xF, 0xF, false);
    return __int_as_float(x);
}
__device__ __forceinline__ float qsum2(float v) { return v + dpp_xor1(v); }

__device__ __forceinline__ float gelu_exact(float x) {
    return 0.5f * x * (1.0f + erff(x * 0.70710678118654752440f));
}

__global__ void __launch_bounds__(256, 1) pinod_kernel(
    const float* __restrict__ expr,
    const float* __restrict__ t_eval,
    const float* __restrict__ enc_w1,
    const float* __restrict__ enc_b1,
    const float* __restrict__ ln_g,
    const float* __restrict__ ln_b,
    const float* __restrict__ enc_w2,
    const float* __restrict__ enc_b2,
    const float* __restrict__ enc_w3,
    const float* __restrict__ enc_b3,
    const float* __restrict__ periods,
    const float* __restrict__ gammav,
    const float* __restrict__ ode_w1,
    const float* __restrict__ ode_b1,
    const float* __restrict__ ode_w2,
    const float* __restrict__ ode_b2,
    const float* __restrict__ dec_w,
    const float* __restrict__ dec_b,
    const float* __restrict__ baseline,
    float* __restrict__ out)
{
    const int tid    = blockIdx.x * 256 + threadIdx.x;
    const int lane   = threadIdx.x & 63;
    const int sub    = tid & 1;          // which half of the hidden units
    const int b      = tid >> 1;         // element id (lane pair {2i,2i+1})
    const int base16 = sub * 16;         // encoder h-unit slice
    const int obase  = sub * 8;          // ODE hidden-unit slice

    float* out_eh  = out;                                          // [NB][NT]
    float* out_tr  = out + (size_t)NB * NT;                        // [NT][NB][NS]
    float* out_amp = out + (size_t)NB * NT + (size_t)NT * NB * NS; // [NB][NK]

    const float C = 2.88539008177792681472f;   // 2*log2(e), folded into w1/b1

    // t_eval preloaded into one VGPR (lane i holds t_eval[i]); per-t access is
    // a v_readlane — removes 47 uniform-load full-wave stalls from the t-loop.
    float tv = t_eval[lane < NT ? lane : NT - 1];

    // ======== ODE weights as SCALARS, algebraically folded + pinned ========
    // w1s[i][u] = C * ode_w1[i][obase+u]   (8 local hidden units per lane)
    float w1s[NS][8];
    #pragma unroll
    for (int i = 0; i < NS; ++i) {
        float4 wA = *(const float4*)(ode_w1 + i * NOH + obase);
        float4 wB = *(const float4*)(ode_w1 + i * NOH + obase + 4);
        w1s[i][0] = C * wA.x; w1s[i][1] = C * wA.y; w1s[i][2] = C * wA.z; w1s[i][3] = C * wA.w;
        w1s[i][4] = C * wB.x; w1s[i][5] = C * wB.y; w1s[i][6] = C * wB.z; w1s[i][7] = C * wB.w;
    }
    float b1s[8];
    {
        float4 wA = *(const float4*)(ode_b1 + obase);
        float4 wB = *(const float4*)(ode_b1 + obase + 4);
        b1s[0] = C * wA.x; b1s[1] = C * wA.y; b1s[2] = C * wA.z; b1s[3] = C * wA.w;
        b1s[4] = C * wB.x; b1s[5] = C * wB.y; b1s[6] = C * wB.z; b1s[7] = C * wB.w;
    }
    // y = 1 - 2*rc where rc = 1/(exp2(a')+1).  pd = sum_j y_j w2_j + b2
    //   = [0.5*b2 + sum_j w2_j] + sum_j rc_j * (-2 w2_j)   (per-lane halves; x2 via dpp sum)
    float w2n[8][NS];      // -2 * ode_w2 rows (this lane's 8 hidden units)
    float hb2s[NS];        // 0.5*b2 + sum of this lane's raw w2 rows
    #pragma unroll
    for (int o = 0; o < NS; ++o) hb2s[o] = 0.5f * ode_b2[o];
    #pragma unroll
    for (int j = 0; j < 8; ++j) {
        const float* wp = ode_w2 + (obase + j) * NS;
        #pragma unroll
        for (int o = 0; o < NS; ++o) {
            float w = wp[o];
            hb2s[o] += w;
            w2n[j][o] = -2.0f * w;
        }
    }
    // linear-dynamics scalar constants (SGPR-resident): d.y = -om2*x - 2g*v + pd.y
    float c1y[NK], c2y[NK], dw[NK];
    #pragma unroll
    for (int k = 0; k < NK; ++k) {
        float w = 6.28318530717958647693f / uni(periods[k]);
        c1y[k] = uni(-(w * w));
        c2y[k] = uni(-2.0f * gammav[k]);
        dw[k]  = uni(dec_w[k]);
    }
    const float addc = uni(dec_b[0] + baseline[0]);

    #pragma unroll
    for (int i = 0; i < NS; ++i)
        #pragma unroll
        for (int u = 0; u < 8; ++u) PIN_V(w1s[i][u]);
    #pragma unroll
    for (int u = 0; u < 8; ++u) PIN_V(b1s[u]);
    #pragma unroll
    for (int j = 0; j < 8; ++j)
        #pragma unroll
        for (int o = 0; o < NS; ++o) PIN_V(w2n[j][o]);
    #pragma unroll
    for (int o = 0; o < NS; ++o) PIN_V(hb2s[o]);

    // ================= encoder (2-way split: 16 h-units per lane) ============
    float h1r[16];
    #pragma unroll
    for (int q = 0; q < 4; ++q) {
        float4 bv = *(const float4*)(enc_b1 + base16 + 4 * q);
        h1r[4 * q] = bv.x; h1r[4 * q + 1] = bv.y; h1r[4 * q + 2] = bv.z; h1r[4 * q + 3] = bv.w;
    }
    const float4* xp = (const float4*)(expr + (size_t)b * NT);
    #pragma unroll 1
    for (int t4 = 0; t4 < NT / 4; ++t4) {
        float4 xq = xp[t4];
        float xs[4] = {xq.x, xq.y, xq.z, xq.w};
        #pragma unroll
        for (int u4 = 0; u4 < 4; ++u4) {
            const float* wr = enc_w1 + (t4 * 4 + u4) * NH + base16;
            float x = xs[u4];
            #pragma unroll
            for (int q = 0; q < 4; ++q) {
                float4 w = *(const float4*)(wr + 4 * q);
                h1r[4 * q]     = fmaf(x, w.x, h1r[4 * q]);
                h1r[4 * q + 1] = fmaf(x, w.y, h1r[4 * q + 1]);
                h1r[4 * q + 2] = fmaf(x, w.z, h1r[4 * q + 2]);
                h1r[4 * q + 3] = fmaf(x, w.w, h1r[4 * q + 3]);
            }
        }
    }
    // layernorm across all 32 (1-stage cross-lane) + gelu
    {
        float s = 0.f;
        #pragma unroll
        for (int u = 0; u < 16; ++u) s += h1r[u];
        float mu = qsum2(s) * (1.0f / NH);
        float v = 0.f;
        #pragma unroll
        for (int u = 0; u < 16; ++u) { float d = h1r[u] - mu; v = fmaf(d, d, v); }
        float var = qsum2(v) * (1.0f / NH);
        float rstd = rsqrtf(var + 1e-5f);
        #pragma unroll
        for (int q = 0; q < 4; ++q) {
            float4 g = *(const float4*)(ln_g + base16 + 4 * q);
            float4 l = *(const float4*)(ln_b + base16 + 4 * q);
            h1r[4 * q]     = gelu_exact((h1r[4 * q]     - mu) * rstd * g.x + l.x);
            h1r[4 * q + 1] = gelu_exact((h1r[4 * q + 1] - mu) * rstd * g.y + l.y);
            h1r[4 * q + 2] = gelu_exact((h1r[4 * q + 2] - mu) * rstd * g.z + l.z);
            h1r[4 * q + 3] = gelu_exact((h1r[4 * q + 3] - mu) * rstd * g.w + l.w);
        }
    }
    // h2 = gelu(h1 @ w2 + b2): lane owns j2 in [base16, base16+16)
    float acc[16];
    #pragma unroll
    for (int q = 0; q < 4; ++q) {
        float4 bv = *(const float4*)(enc_b2 + base16 + 4 * q);
        acc[4 * q] = bv.x; acc[4 * q + 1] = bv.y; acc[4 * q + 2] = bv.z; acc[4 * q + 3] = bv.w;
    }
    #pragma unroll 1
    for (int u = 0; u < 16; ++u) {
        float mine  = h1r[u];
        float other = dpp_xor1(mine);
        const float* wa = enc_w2 + (base16 + u) * NH + base16;
        const float* wb = enc_w2 + ((16 - base16) + u) * NH + base16;
        #pragma unroll
        for (int q = 0; q < 4; ++q) {
            float4 w1v = *(const float4*)(wa + 4 * q);
            float4 w2v = *(const float4*)(wb + 4 * q);
            acc[4 * q]     = fmaf(mine, w1v.x, fmaf(other, w2v.x, acc[4 * q]));
            acc[4 * q + 1] = fmaf(mine, w1v.y, fmaf(other, w2v.y, acc[4 * q + 1]));
            acc[4 * q + 2] = fmaf(mine, w1v.z, fmaf(other, w2v.z, acc[4 * q + 2]));
            acc[4 * q + 3] = fmaf(mine, w1v.w, fmaf(other, w2v.w, acc[4 * q + 3]));
        }
    }
    // z0 = gelu(acc) @ w3 + b3, 1-stage reduce -> replicated in both lanes
    f2 z[3];
    {
        float zp[NS] = {0.f, 0.f, 0.f, 0.f, 0.f, 0.f};
        #pragma unroll 1
        for (int u = 0; u < 16; ++u) {
            float gm = gelu_exact(acc[u]);
            const float2* wp = (const float2*)(enc_w3 + (base16 + u) * NS);
            float2 w0 = wp[0], w1 = wp[1], w2 = wp[2];
            zp[0] = fmaf(gm, w0.x, zp[0]); zp[1] = fmaf(gm, w0.y, zp[1]);
            zp[2] = fmaf(gm, w1.x, zp[2]); zp[3] = fmaf(gm, w1.y, zp[3]);
            zp[4] = fmaf(gm, w2.x, zp[4]); zp[5] = fmaf(gm, w2.y, zp[5]);
        }
        #pragma unroll
        for (int s = 0; s < 3; ++s) {
            z[s].x = qsum2(zp[2 * s])     + enc_b3[2 * s];
            z[s].y = qsum2(zp[2 * s + 1]) + enc_b3[2 * s + 1];
        }
    }

    // ===================== deriv — pure scalar fmaf, no inline asm ==========
    auto deriv = [&](const f2 (&zz)[3], f2 (&d)[3]) {
        // a[u] = C*(b1[u] + sum_i z_i w1[i][u]) — two independent 3-deep chains
        float av[8];
        #pragma unroll
        for (int u = 0; u < 8; ++u) {
            float cA = fmaf(zz[0].x, w1s[0][u], b1s[u]);
            float cB = zz[0].y * w1s[1][u];
            cA = fmaf(zz[1].x, w1s[2][u], cA);
            cB = fmaf(zz[1].y, w1s[3][u], cB);
            cA = fmaf(zz[2].x, w1s[4][u], cA);
            cB = fmaf(zz[2].y, w1s[5][u], cB);
            av[u] = cA + cB;
        }
        // rc = 1/(exp2(a)+1) — independent trans chains per unit (R4 numerics)
        float rc[8];
        #pragma unroll
        for (int u = 0; u < 8; ++u) {
            float e = __builtin_amdgcn_exp2f(av[u]);
            rc[u] = __builtin_amdgcn_rcpf(e + 1.0f);
        }
        // pd[o] = hb2s[o] + sum_j rc_j * w2n[j][o] — two 4-deep chains per o
        float p[NS];
        #pragma unroll
        for (int o = 0; o < NS; ++o) {
            float pA = fmaf(rc[0], w2n[0][o], hb2s[o]);
            float pB = rc[1] * w2n[1][o];
            pA = fmaf(rc[2], w2n[2][o], pA);
            pB = fmaf(rc[3], w2n[3][o], pB);
            pA = fmaf(rc[4], w2n[4][o], pA);
            pB = fmaf(rc[5], w2n[5][o], pB);
            pA = fmaf(rc[6], w2n[6][o], pA);
            pB = fmaf(rc[7], w2n[7][o], pB);
            p[o] = qsum2(pA + pB);
        }
        // linear assembly: d.x = v + p[2k]; d.y = -2g*v + (-om2*x + p[2k+1])
        #pragma unroll
        for (int k = 0; k < 3; ++k) {
            d[k].x = zz[k].y + p[2 * k];
            d[k].y = fmaf(zz[k].y, c2y[k], fmaf(zz[k].x, c1y[k], p[2 * k + 1]));
        }
    };

    // ================= per-t outputs =================
    float amp[NK];
    auto emit = [&](int t, bool init) {
        float eh = addc;
        #pragma unroll
        for (int k = 0; k < NK; ++k) {
            float xx = z[k].x;
            amp[k] = init ? (xx * xx) : fmaf(xx, xx, amp[k]);
            eh = fmaf(xx, dw[k], eh);
        }
        float* tp = out_tr + ((size_t)t * NB + b) * NS;
        // balanced stores: lane0 -> {z0 pair, z1 pair}; lane1 -> {z2 pair, eh}
        f2 zpr = sub ? z[2] : z[0];
        float2 pv = {zpr.x, zpr.y};
        *(float2*)(tp + 4 * sub) = pv;
        if (sub == 0) {
            float2 s1v = {z[1].x, z[1].y};
            *(float2*)(tp + 2) = s1v;
        } else {
            out_eh[(size_t)b * NT + t] = eh;
        }
    };

    emit(0, true);

    // ================= integrate =================
    float te_prev = lanef(tv, 0);
    #pragma unroll 1
    for (int t = 1; t < NT; ++t) {
        const float te  = lanef(tv, t);
        const float dt  = te - te_prev;
        te_prev = te;
        const float hh  = dt * (1.0f / NSUB);
        const float hh2 = 0.5f * hh;
        const float hh6 = hh * (1.0f / 6.0f);
        f2 hh2p = bc2(hh2), hhp = bc2(hh), hh6p = bc2(hh6);
        // fully unrolled: scheduler can overlap substep k's tail with k+1's
        // a-chains (which only need z[0] first)
        #pragma unroll
        for (int ss = 0; ss < NSUB; ++ss) {
            f2 d[3], zt[3], zs[3];
            deriv(z, d);                                        // k1
            #pragma unroll
            for (int s = 0; s < 3; ++s) { zs[s] = d[s]; zt[s] = fma2(hh2p, d[s], z[s]); }
            deriv(zt, d);                                       // k2
            #pragma unroll
            for (int s = 0; s < 3; ++s) { zs[s] = fma2(bc2(2.f), d[s], zs[s]); zt[s] = fma2(hh2p, d[s], z[s]); }
            deriv(zt, d);                                       // k3
            #pragma unroll
            for (int s = 0; s < 3; ++s) { zs[s] = fma2(bc2(2.f), d[s], zs[s]); zt[s] = fma2(hhp, d[s], z[s]); }
            deriv(zt, d);                                       // k4
            #pragma unroll
            for (int s = 0; s < 3; ++s) z[s] = fma2(hh6p, zs[s] + d[s], z[s]);
        }
        emit(t, false);
    }

    if (sub == 0) {
        out_amp[(size_t)b * NK]     = sqrtf(amp[0] * (1.0f / NT));
        out_amp[(size_t)b * NK + 1] = sqrtf(amp[1] * (1.0f / NT));
    } else {
        out_amp[(size_t)b * NK + 2] = sqrtf(amp[2] * (1.0f / NT));
    }
}

extern "C" void kernel_launch(void* const* d_in, const int* in_sizes, int n_in,
                              void* d_out, int out_size, void* d_ws, size_t ws_size,
                              hipStream_t stream) {
    pinod_kernel<<<(NB * 2) / 256, 256, 0, stream>>>(
        (const float*)d_in[0],  (const float*)d_in[1],  (const float*)d_in[2],
        (const float*)d_in[3],  (const float*)d_in[4],  (const float*)d_in[5],
        (const float*)d_in[6],  (const float*)d_in[7],  (const float*)d_in[8],
        (const float*)d_in[9],  (const float*)d_in[10], (const float*)d_in[11],
        (const float*)d_in[12], (const float*)d_in[13], (const float*)d_in[14],
        (const float*)d_in[15], (const float*)d_in[16], (const float*)d_in[17],
        (const float*)d_in[18], (float*)d_out);
}

// Round 7
// 293.887 us; speedup vs baseline: 1.0490x; 1.0490x over previous
//
#include <hip/hip_runtime.h>
#include <math.h>

#define NB 32768
#define NT 48
#define NH 32
#define NOH 16
#define NK 3
#define NS 6
#define NSUB 4

typedef float f2 __attribute__((ext_vector_type(2)));

// Force a value/pair to stay live in VGPRs (compiler cannot rematerialize)
#define PIN_V(x) asm volatile("" : "+v"(x))
// Make a wave-uniform float SGPR-resident (legal VGPR->SGPR via readfirstlane)
__device__ __forceinline__ float uni(float x) {
    return __int_as_float(__builtin_amdgcn_readfirstlane(__float_as_int(x)));
}
// wave-uniform lane-gather (value was loaded per-lane; index is SGPR-uniform)
__device__ __forceinline__ float lanef(float v, int l) {
    return __int_as_float(__builtin_amdgcn_readlane(__float_as_int(v), l));
}

// packed fma, src0 scalar-broadcast via op_sel (verified semantics in prior session):
//   LO: acc.{x,y} += zp.x * w.{x,y}      HI: acc.{x,y} += zp.y * w.{x,y}
#define PK_FMA_LO(acc, zp, w) \
    asm("v_pk_fma_f32 %0, %1, %2, %0 op_sel:[0,0,0] op_sel_hi:[0,1,1]" \
        : "+v"(acc) : "v"(zp), "v"(w))
#define PK_FMA_HI(acc, zp, w) \
    asm("v_pk_fma_f32 %0, %1, %2, %0 op_sel:[1,0,0] op_sel_hi:[1,1,1]" \
        : "+v"(acc) : "v"(zp), "v"(w))
// init forms: dst = bcast(zp)*w + c   (no accumulator-copy mov)
#define PK_FMA_LO_I(dst, zp, w, c) \
    asm("v_pk_fma_f32 %0, %1, %2, %3 op_sel:[0,0,0] op_sel_hi:[0,1,1]" \
        : "=v"(dst) : "v"(zp), "v"(w), "v"(c))
// mul-init form: dst = bcast(zp.y)*w   (starts the HI chain without a zero/copy)
#define PK_MUL_HI_I(dst, zp, w) \
    asm("v_pk_mul_f32 %0, %1, %2 op_sel:[1,0] op_sel_hi:[1,1]" \
        : "=v"(dst) : "v"(zp), "v"(w))

__device__ __forceinline__ f2 fma2(f2 a, f2 b, f2 c) {
    return __builtin_elementwise_fma(a, b, c);
}
__device__ __forceinline__ f2 bc2(float x) { f2 r; r.x = x; r.y = x; return r; }

// partner-lane value via DPP quad_perm [1,0,3,2] (xor lane^1) — VALU pipe
__device__ __forceinline__ float dpp_xor1(float v) {
    int x = __builtin_amdgcn_update_dpp(0, __float_as_int(v), 0xB1, 0xF, 0xF, false);
    return __int_as_float(x);
}
__device__ __forceinline__ float qsum2(float v) { return v + dpp_xor1(v); }

__device__ __forceinline__ float gelu_exact(float x) {
    return 0.5f * x * (1.0f + erff(x * 0.70710678118654752440f));
}

__global__ void __launch_bounds__(256, 1) pinod_kernel(
    const float* __restrict__ expr,
    const float* __restrict__ t_eval,
    const float* __restrict__ enc_w1,
    const float* __restrict__ enc_b1,
    const float* __restrict__ ln_g,
    const float* __restrict__ ln_b,
    const float* __restrict__ enc_w2,
    const float* __restrict__ enc_b2,
    const float* __restrict__ enc_w3,
    const float* __restrict__ enc_b3,
    const float* __restrict__ periods,
    const float* __restrict__ gammav,
    const float* __restrict__ ode_w1,
    const float* __restrict__ ode_b1,
    const float* __restrict__ ode_w2,
    const float* __restrict__ ode_b2,
    const float* __restrict__ dec_w,
    const float* __restrict__ dec_b,
    const float* __restrict__ baseline,
    float* __restrict__ out)
{
    const int tid    = blockIdx.x * 256 + threadIdx.x;
    const int lane   = threadIdx.x & 63;
    const int sub    = tid & 1;          // which half of the hidden units
    const int b      = tid >> 1;         // element id (lane pair {2i,2i+1})
    const int base16 = sub * 16;         // encoder h-unit slice
    const int obase  = sub * 8;          // ODE hidden-unit slice

    float* out_eh  = out;                                          // [NB][NT]
    float* out_tr  = out + (size_t)NB * NT;                        // [NT][NB][NS]
    float* out_amp = out + (size_t)NB * NT + (size_t)NT * NB * NS; // [NB][NK]

    const float C = 2.88539008177792681472f;   // 2*log2(e), folded into w1/b1

    // t_eval preloaded into one VGPR (lane i holds t_eval[i]); per-t access is
    // a v_readlane — removes 47 uniform-load full-wave stalls from the t-loop.
    float tv = t_eval[lane < NT ? lane : NT - 1];

    // ======== ODE weights as f2 pairs, algebraically folded + pinned ========
    // w1p[i][p] = C * ode_w1[i][obase+2p .. +1]
    f2 w1p[NS][4];
    #pragma unroll
    for (int i = 0; i < NS; ++i) {
        float4 wA = *(const float4*)(ode_w1 + i * NOH + obase);
        float4 wB = *(const float4*)(ode_w1 + i * NOH + obase + 4);
        w1p[i][0].x = C * wA.x; w1p[i][0].y = C * wA.y;
        w1p[i][1].x = C * wA.z; w1p[i][1].y = C * wA.w;
        w1p[i][2].x = C * wB.x; w1p[i][2].y = C * wB.y;
        w1p[i][3].x = C * wB.z; w1p[i][3].y = C * wB.w;
    }
    f2 b1p[4];
    {
        float4 wA = *(const float4*)(ode_b1 + obase);
        float4 wB = *(const float4*)(ode_b1 + obase + 4);
        b1p[0].x = C * wA.x; b1p[0].y = C * wA.y; b1p[1].x = C * wA.z; b1p[1].y = C * wA.w;
        b1p[2].x = C * wB.x; b1p[2].y = C * wB.y; b1p[3].x = C * wB.z; b1p[3].y = C * wB.w;
    }
    // y = 1 - 2*rc where rc = 1/(exp2(a')+1).  pd = sum_j y_j w2_j + b2
    //   = [0.5*b2 + sum_j w2_j] + sum_j rc_j * (-2 w2_j)   (per-lane halves; x2 via dpp sum)
    f2 w2p[8][3];      // -2 * ode_w2 rows
    f2 hb2p[3];        // 0.5*b2 + sum of this lane's raw w2 rows
    #pragma unroll
    for (int s = 0; s < 3; ++s) {
        float2 w = *(const float2*)(ode_b2 + 2 * s);
        hb2p[s].x = 0.5f * w.x; hb2p[s].y = 0.5f * w.y;
    }
    #pragma unroll
    for (int j = 0; j < 8; ++j) {
        const float2* wp = (const float2*)(ode_w2 + (obase + j) * NS);
        #pragma unroll
        for (int s = 0; s < 3; ++s) {
            float2 w = wp[s];
            hb2p[s].x += w.x;          hb2p[s].y += w.y;
            w2p[j][s].x = -2.0f * w.x; w2p[j][s].y = -2.0f * w.y;
        }
    }
    // linear-dynamics scalar constants (SGPR-resident): d.y = -om2*x - 2g*v + pd.y
    float c1y[NK], c2y[NK], dw[NK];
    #pragma unroll
    for (int k = 0; k < NK; ++k) {
        float w = 6.28318530717958647693f / uni(periods[k]);
        c1y[k] = uni(-(w * w));
        c2y[k] = uni(-2.0f * gammav[k]);
        dw[k]  = uni(dec_w[k]);
    }
    const float addc = uni(dec_b[0] + baseline[0]);

    #pragma unroll
    for (int i = 0; i < NS; ++i)
        #pragma unroll
        for (int p = 0; p < 4; ++p) PIN_V(w1p[i][p]);
    #pragma unroll
    for (int p = 0; p < 4; ++p) PIN_V(b1p[p]);
    #pragma unroll
    for (int j = 0; j < 8; ++j)
        #pragma unroll
        for (int s = 0; s < 3; ++s) PIN_V(w2p[j][s]);
    #pragma unroll
    for (int s = 0; s < 3; ++s) PIN_V(hb2p[s]);

    // ================= encoder (2-way split: 16 h-units per lane) ============
    float h1r[16];
    #pragma unroll
    for (int q = 0; q < 4; ++q) {
        float4 bv = *(const float4*)(enc_b1 + base16 + 4 * q);
        h1r[4 * q] = bv.x; h1r[4 * q + 1] = bv.y; h1r[4 * q + 2] = bv.z; h1r[4 * q + 3] = bv.w;
    }
    const float4* xp = (const float4*)(expr + (size_t)b * NT);
    #pragma unroll 1
    for (int t4 = 0; t4 < NT / 4; ++t4) {
        float4 xq = xp[t4];
        float xs[4] = {xq.x, xq.y, xq.z, xq.w};
        #pragma unroll
        for (int u4 = 0; u4 < 4; ++u4) {
            const float* wr = enc_w1 + (t4 * 4 + u4) * NH + base16;
            float x = xs[u4];
            #pragma unroll
            for (int q = 0; q < 4; ++q) {
                float4 w = *(const float4*)(wr + 4 * q);
                h1r[4 * q]     = fmaf(x, w.x, h1r[4 * q]);
                h1r[4 * q + 1] = fmaf(x, w.y, h1r[4 * q + 1]);
                h1r[4 * q + 2] = fmaf(x, w.z, h1r[4 * q + 2]);
                h1r[4 * q + 3] = fmaf(x, w.w, h1r[4 * q + 3]);
            }
        }
    }
    // layernorm across all 32 (1-stage cross-lane) + gelu
    {
        float s = 0.f;
        #pragma unroll
        for (int u = 0; u < 16; ++u) s += h1r[u];
        float mu = qsum2(s) * (1.0f / NH);
        float v = 0.f;
        #pragma unroll
        for (int u = 0; u < 16; ++u) { float d = h1r[u] - mu; v = fmaf(d, d, v); }
        float var = qsum2(v) * (1.0f / NH);
        float rstd = rsqrtf(var + 1e-5f);
        #pragma unroll
        for (int q = 0; q < 4; ++q) {
            float4 g = *(const float4*)(ln_g + base16 + 4 * q);
            float4 l = *(const float4*)(ln_b + base16 + 4 * q);
            h1r[4 * q]     = gelu_exact((h1r[4 * q]     - mu) * rstd * g.x + l.x);
            h1r[4 * q + 1] = gelu_exact((h1r[4 * q + 1] - mu) * rstd * g.y + l.y);
            h1r[4 * q + 2] = gelu_exact((h1r[4 * q + 2] - mu) * rstd * g.z + l.z);
            h1r[4 * q + 3] = gelu_exact((h1r[4 * q + 3] - mu) * rstd * g.w + l.w);
        }
    }
    // h2 = gelu(h1 @ w2 + b2): lane owns j2 in [base16, base16+16)
    float acc[16];
    #pragma unroll
    for (int q = 0; q < 4; ++q) {
        float4 bv = *(const float4*)(enc_b2 + base16 + 4 * q);
        acc[4 * q] = bv.x; acc[4 * q + 1] = bv.y; acc[4 * q + 2] = bv.z; acc[4 * q + 3] = bv.w;
    }
    #pragma unroll 1
    for (int u = 0; u < 16; ++u) {
        float mine  = h1r[u];
        float other = dpp_xor1(mine);
        const float* wa = enc_w2 + (base16 + u) * NH + base16;
        const float* wb = enc_w2 + ((16 - base16) + u) * NH + base16;
        #pragma unroll
        for (int q = 0; q < 4; ++q) {
            float4 w1v = *(const float4*)(wa + 4 * q);
            float4 w2v = *(const float4*)(wb + 4 * q);
            acc[4 * q]     = fmaf(mine, w1v.x, fmaf(other, w2v.x, acc[4 * q]));
            acc[4 * q + 1] = fmaf(mine, w1v.y, fmaf(other, w2v.y, acc[4 * q + 1]));
            acc[4 * q + 2] = fmaf(mine, w1v.z, fmaf(other, w2v.z, acc[4 * q + 2]));
            acc[4 * q + 3] = fmaf(mine, w1v.w, fmaf(other, w2v.w, acc[4 * q + 3]));
        }
    }
    // z0 = gelu(acc) @ w3 + b3, 1-stage reduce -> replicated in both lanes
    f2 z[3];
    {
        float zp[NS] = {0.f, 0.f, 0.f, 0.f, 0.f, 0.f};
        #pragma unroll 1
        for (int u = 0; u < 16; ++u) {
            float gm = gelu_exact(acc[u]);
            const float2* wp = (const float2*)(enc_w3 + (base16 + u) * NS);
            float2 w0 = wp[0], w1 = wp[1], w2 = wp[2];
            zp[0] = fmaf(gm, w0.x, zp[0]); zp[1] = fmaf(gm, w0.y, zp[1]);
            zp[2] = fmaf(gm, w1.x, zp[2]); zp[3] = fmaf(gm, w1.y, zp[3]);
            zp[4] = fmaf(gm, w2.x, zp[4]); zp[5] = fmaf(gm, w2.y, zp[5]);
        }
        #pragma unroll
        for (int s = 0; s < 3; ++s) {
            z[s].x = qsum2(zp[2 * s])     + enc_b3[2 * s];
            z[s].y = qsum2(zp[2 * s + 1]) + enc_b3[2 * s + 1];
        }
    }

    auto deriv = [&](const f2 (&zz)[3], f2 (&d)[3]) {
        // a'[p] = C*(b1 + sum_i z_i w1[i][p]) — TWO independent chains per p:
        //   aA[p]: LO terms (z0.x, z1.x, z2.x), init from b1p  (3-deep)
        //   aB[p]: HI terms (z0.y, z1.y, z2.y), init via pk_mul (3-deep)
        f2 aA[4], aB[4];
        #pragma unroll
        for (int p = 0; p < 4; ++p) {
            PK_FMA_LO_I(aA[p], zz[0], w1p[0][p], b1p[p]);
            PK_MUL_HI_I(aB[p], zz[0], w1p[1][p]);
        }
        #pragma unroll
        for (int s = 1; s < 3; ++s) {
            #pragma unroll
            for (int p = 0; p < 4; ++p) {
                PK_FMA_LO(aA[p], zz[s], w1p[2 * s][p]);
                PK_FMA_HI(aB[p], zz[s], w1p[2 * s + 1][p]);
            }
        }
        // merge -> exp2 -> +1 -> rcp, p-ascending so pair 0's trans ops issue
        // while pairs 1..3 are still accumulating (trans-latency overlap).
        // Independent trans chains per element (paired-rcp was measured WORSE:
        // it serializes the trans region and adds exposed latency — R5).
        f2 rc[4];
        #pragma unroll
        for (int p = 0; p < 4; ++p) {
            f2 a = aA[p] + aB[p];
            f2 e; e.x = __builtin_amdgcn_exp2f(a.x); e.y = __builtin_amdgcn_exp2f(a.y);
            f2 r = e + bc2(1.0f);
            rc[p].x = __builtin_amdgcn_rcpf(r.x); rc[p].y = __builtin_amdgcn_rcpf(r.y);
        }
        // pd[s] = hb2p + sum_j rc_j * w2p[j] — TWO chains per s (4-deep each),
        // rc consumed in ROTATED order (s, s+1, s+2, s+3 mod 4): chain inits
        // align with staggered rc arrivals and the three tails destagger.
        f2 pdA[3], pdB[3];
        #pragma unroll
        for (int s = 0; s < 3; ++s) {
            PK_FMA_LO_I(pdA[s], rc[s], w2p[2 * s][s], hb2p[s]);
            PK_MUL_HI_I(pdB[s], rc[s], w2p[2 * s + 1][s]);
            #pragma unroll
            for (int j = 1; j < 4; ++j) {
                const int p = (s + j) & 3;
                PK_FMA_LO(pdA[s], rc[p], w2p[2 * p][s]);
                PK_FMA_HI(pdB[s], rc[p], w2p[2 * p + 1][s]);
            }
        }
        // merge + cross-lane reduce + SCALAR linear assembly:
        //   d.x = v + pd.x ;  d.y = -2g*v + (-om2*x + pd.y)
        #pragma unroll
        for (int s = 0; s < 3; ++s) {
            f2 pd = pdA[s] + pdB[s];
            f2 o; o.x = dpp_xor1(pd.x); o.y = dpp_xor1(pd.y);
            pd += o;
            d[s].x = zz[s].y + pd.x;
            d[s].y = fmaf(zz[s].y, c2y[s], fmaf(zz[s].x, c1y[s], pd.y));
        }
    };

    // ================= per-t outputs =================
    float amp[NK];
    auto emit = [&](int t, bool init) {
        float eh = addc;
        #pragma unroll
        for (int k = 0; k < NK; ++k) {
            float xx = z[k].x;
            amp[k] = init ? (xx * xx) : fmaf(xx, xx, amp[k]);
            eh = fmaf(xx, dw[k], eh);
        }
        float* tp = out_tr + ((size_t)t * NB + b) * NS;
        // balanced stores: lane0 -> {z0 pair, z1 pair}; lane1 -> {z2 pair, eh}
        f2 zpr = sub ? z[2] : z[0];
        float2 pv = {zpr.x, zpr.y};
        *(float2*)(tp + 4 * sub) = pv;
        if (sub == 0) {
            float2 s1v = {z[1].x, z[1].y};
            *(float2*)(tp + 2) = s1v;
        } else {
            out_eh[(size_t)b * NT + t] = eh;
        }
    };

    emit(0, true);

    // ================= integrate =================
    float te_prev = lanef(tv, 0);
    #pragma unroll 1
    for (int t = 1; t < NT; ++t) {
        const float te  = lanef(tv, t);
        const float dt  = te - te_prev;
        te_prev = te;
        const float hh  = dt * (1.0f / NSUB);
        const float hh2 = 0.5f * hh;
        const float hh6 = hh * (1.0f / 6.0f);
        f2 hh2p = bc2(hh2), hhp = bc2(hh), hh6p = bc2(hh6);
        // fully unrolled: scheduler can overlap substep k's tail with k+1's
        // a-chains (which only need z[0] first)
        #pragma unroll
        for (int ss = 0; ss < NSUB; ++ss) {
            f2 d[3], zt[3], zs[3];
            deriv(z, d);                                        // k1
            #pragma unroll
            for (int s = 0; s < 3; ++s) { zs[s] = d[s]; zt[s] = fma2(hh2p, d[s], z[s]); }
            deriv(zt, d);                                       // k2
            #pragma unroll
            for (int s = 0; s < 3; ++s) { zs[s] = fma2(bc2(2.f), d[s], zs[s]); zt[s] = fma2(hh2p, d[s], z[s]); }
            deriv(zt, d);                                       // k3
            #pragma unroll
            for (int s = 0; s < 3; ++s) { zs[s] = fma2(bc2(2.f), d[s], zs[s]); zt[s] = fma2(hhp, d[s], z[s]); }
            deriv(zt, d);                                       // k4
            #pragma unroll
            for (int s = 0; s < 3; ++s) z[s] = fma2(hh6p, zs[s] + d[s], z[s]);
        }
        emit(t, false);
    }

    if (sub == 0) {
        out_amp[(size_t)b * NK]     = sqrtf(amp[0] * (1.0f / NT));
        out_amp[(size_t)b * NK + 1] = sqrtf(amp[1] * (1.0f / NT));
    } else {
        out_amp[(size_t)b * NK + 2] = sqrtf(amp[2] * (1.0f / NT));
    }
}

extern "C" void kernel_launch(void* const* d_in, const int* in_sizes, int n_in,
                              void* d_out, int out_size, void* d_ws, size_t ws_size,
                              hipStream_t stream) {
    pinod_kernel<<<(NB * 2) / 256, 256, 0, stream>>>(
        (const float*)d_in[0],  (const float*)d_in[1],  (const float*)d_in[2],
        (const float*)d_in[3],  (const float*)d_in[4],  (const float*)d_in[5],
        (const float*)d_in[6],  (const float*)d_in[7],  (const float*)d_in[8],
        (const float*)d_in[9],  (const float*)d_in[10], (const float*)d_in[11],
        (const float*)d_in[12], (const float*)d_in[13], (const float*)d_in[14],
        (const float*)d_in[15], (const float*)d_in[16], (const float*)d_in[17],
        (const float*)d_in[18], (float*)d_out);
}